// Round 9
// baseline (349.368 us; speedup 1.0000x reference)
//
#include <hip/hip_runtime.h>
#include <math.h>

// Problem constants (fixed by the reference)
#define BB     2
#define LL     1024
#define CC     4
#define EE     256
#define HH     8
#define DD     32
#define NLAYER 2
#define W1N    257          // WIN+1
#define INPAIR 1028         // C*(WIN+1)
#define KP1    1056         // INPAIR padded to 32
#define HIDN   512
#define NCN    10
#define SCALEF 0.17677669529663687f   // 32^-0.5

typedef short bf16x8 __attribute__((ext_vector_type(8)));
typedef float f32x4  __attribute__((ext_vector_type(4)));
typedef unsigned short u16x4 __attribute__((ext_vector_type(4)));
typedef unsigned short u16x8 __attribute__((ext_vector_type(8)));

__device__ __forceinline__ float gelu_f(float x) {
    return 0.5f * x * (1.0f + erff(x * 0.7071067811865475f));
}
__device__ __forceinline__ unsigned short f2bf(float f) {
    unsigned u = __float_as_uint(f);
    u += 0x7fffu + ((u >> 16) & 1u);      // RNE
    return (unsigned short)(u >> 16);
}

// ---------------------------------------------------------------------------
// prep_gather: one launch for both weight conversion and the pairwise gather.
// ---------------------------------------------------------------------------
struct PrepDesc {
    const float* src[14];
    int K[14];
    int N[14];
    unsigned long long dst[14];
};

__global__ __launch_bounds__(256) void prep_gather(
    PrepDesc pd, unsigned short* __restrict__ wt,
    const float* __restrict__ xp, unsigned short* __restrict__ flat)
{
    const int bid = blockIdx.x;
    if (bid < 1848) {
        const int mi = bid / 132, k8 = bid - mi * 132;
        const int K = pd.K[mi], N = pd.N[mi];
        const int Kp = (K + 31) & ~31;
        if (k8 * 8 >= Kp) return;
        const float* src = pd.src[mi];
        unsigned short* dst = wt + pd.dst[mi];
        for (int n = threadIdx.x; n < N; n += 256) {
            u16x8 o;
            #pragma unroll
            for (int j = 0; j < 8; ++j) {
                int k = k8 * 8 + j;
                float v = (k < K) ? src[(size_t)k * N + n] : 0.f;
                o[j] = f2bf(v);
            }
            *(u16x8*)(dst + ((size_t)k8 * N + n) * 8) = o;
        }
    } else {
        const int row = bid - 1848;
        const int b = row >> 10, l = row & 1023;
        const float* base = xp + (size_t)b * CC * LL * LL + (size_t)l * LL;
        for (int kp = threadIdx.x; kp < KP1; kp += 256) {
            float v = 0.f;
            if (kp < INPAIR) {
                int c = kp / W1N;
                int w = kp - c * W1N;
                int col = l + w - 128;
                if (col >= 0 && col < LL) v = base[(size_t)c * LL * LL + col];
            }
            flat[(size_t)row * KP1 + kp] = f2bf(v);
        }
    }
}

// ---------------------------------------------------------------------------
// gemm_mfma: out = epi(A_bf16 @ W + bias). No LDS, no barriers.
// (unchanged from R8; used for MLP1, MLP2, O-proj, FFN2)
// ---------------------------------------------------------------------------
template<int KP, int EPI>
__global__ __launch_bounds__(256) void gemm_mfma(
    const unsigned short* __restrict__ A,
    const unsigned short* wt0, const float* b0, void* o0,
    const unsigned short* wt1, const float* b1, void* o1,
    const unsigned short* wt2, const float* b2, void* o2,
    int N,
    const int* __restrict__ tokens, const float* __restrict__ temb,
    const float* __restrict__ pe)
{
    const int t = threadIdx.x;
    const int w = t >> 6, lane = t & 63;
    const int m0 = blockIdx.x * 64 + w * 16;
    const int n0 = blockIdx.y * 16;
    const unsigned short* WT; const float* bias; void* out;
    if (blockIdx.z == 0)      { WT = wt0; bias = b0; out = o0; }
    else if (blockIdx.z == 1) { WT = wt1; bias = b1; out = o1; }
    else                      { WT = wt2; bias = b2; out = o2; }

    const int q = lane >> 4, li = lane & 15;
    const unsigned short* ap = A + (size_t)(m0 + li) * KP + q * 8;
    const unsigned short* bp = WT + ((size_t)q * N + n0 + li) * 8;
    f32x4 acc = {0.f, 0.f, 0.f, 0.f};
    for (int ks = 0; ks < KP / 32; ++ks) {
        bf16x8 av = *(const bf16x8*)(ap + ks * 32);
        bf16x8 bv = *(const bf16x8*)(bp + (size_t)ks * 32 * N);
        acc = __builtin_amdgcn_mfma_f32_16x16x32_bf16(av, bv, acc, 0, 0, 0);
    }

    const int colg = n0 + li;
    const float bb = bias[colg];
    const int rbase = m0 + q * 4;
    #pragma unroll
    for (int r = 0; r < 4; ++r) {
        const int row = rbase + r;
        float v = acc[r] + bb;
        if constexpr (EPI == 1) {          // residual accumulate into fp32 out
            float* op = (float*)out;
            op[(size_t)row * N + colg] += v;
        } else if constexpr (EPI == 2) {   // gelu -> bf16
            ((unsigned short*)out)[(size_t)row * N + colg] = f2bf(gelu_f(v));
        } else if constexpr (EPI == 3) {   // relu -> bf16
            ((unsigned short*)out)[(size_t)row * N + colg] = f2bf(fmaxf(v, 0.f));
        } else {                            // emb: + temb[tok] + pe -> fp32
            int tok = tokens[row];
            v += temb[(size_t)tok * EE + colg] + pe[(size_t)(row & 1023) * EE + colg];
            ((float*)out)[(size_t)row * EE + colg] = v;
        }
    }
}

// ---------------------------------------------------------------------------
// gemm_ln_mfma: LayerNorm fused GEMM. Block = 64 rows x 64 cols, 4 waves.
// LN of the 64 rows computed ONCE per block into LDS (bf16, pad to 264),
// then each wave does 4 row-tiles of one 16-col tile, reusing each
// B-fragment across the 4 row-tiles.
// EPI: 0=QKV pack (blockIdx.z: 0=Q A-layout, 1=K swz, 2=V swz), 2=gelu->bf16
// Grid: QKV (32,4,3) N=256; FFN1 (32,8,1) N=512.
// ---------------------------------------------------------------------------
template<int EPI>
__global__ __launch_bounds__(256) void gemm_ln_mfma(
    const float* __restrict__ X,
    const float* __restrict__ lng, const float* __restrict__ lnb,
    const unsigned short* wt0, const float* b0, void* o0,
    const unsigned short* wt1, const float* b1, void* o1,
    const unsigned short* wt2, const float* b2, void* o2,
    int N)
{
    __shared__ unsigned short xs[64][264];
    const int t = threadIdx.x;
    const int m0 = blockIdx.x * 64;

    // ---- LN stage: 4 threads per row (consecutive lanes), 64 cols each ----
    {
        const int r = t >> 2, qq = t & 3;
        const float* xr = X + (size_t)(m0 + r) * EE + qq * 64;
        float4 v[16];
        float s1 = 0.f, s2 = 0.f;
        #pragma unroll
        for (int j = 0; j < 16; ++j) {
            v[j] = *(const float4*)(xr + j * 4);
            s1 += v[j].x + v[j].y + v[j].z + v[j].w;
            s2 = fmaf(v[j].x, v[j].x, s2); s2 = fmaf(v[j].y, v[j].y, s2);
            s2 = fmaf(v[j].z, v[j].z, s2); s2 = fmaf(v[j].w, v[j].w, s2);
        }
        s1 += __shfl_xor(s1, 1, 64); s1 += __shfl_xor(s1, 2, 64);
        s2 += __shfl_xor(s2, 1, 64); s2 += __shfl_xor(s2, 2, 64);
        const float mu = s1 * (1.0f / 256.0f);
        const float var = s2 * (1.0f / 256.0f) - mu * mu;
        const float rstd = rsqrtf(fmaxf(var, 0.f) + 1e-5f);
        unsigned short* dst = &xs[r][qq * 64];
        #pragma unroll
        for (int j = 0; j < 16; ++j) {
            float4 gg = *(const float4*)(lng + qq * 64 + j * 4);
            float4 bb = *(const float4*)(lnb + qq * 64 + j * 4);
            u16x4 o;
            o[0] = f2bf((v[j].x - mu) * rstd * gg.x + bb.x);
            o[1] = f2bf((v[j].y - mu) * rstd * gg.y + bb.y);
            o[2] = f2bf((v[j].z - mu) * rstd * gg.z + bb.z);
            o[3] = f2bf((v[j].w - mu) * rstd * gg.w + bb.w);
            *(u16x4*)(dst + j * 4) = o;
        }
    }
    __syncthreads();

    // ---- MFMA stage: wave w -> col tile (by*64 + w*16), 4 row-tiles ----
    const int w = t >> 6, lane = t & 63;
    const int q = lane >> 4, li = lane & 15;
    const unsigned short* WT; const float* bias; void* out;
    if (blockIdx.z == 0)      { WT = wt0; bias = b0; out = o0; }
    else if (blockIdx.z == 1) { WT = wt1; bias = b1; out = o1; }
    else                      { WT = wt2; bias = b2; out = o2; }
    const int n0 = blockIdx.y * 64 + w * 16;
    const unsigned short* bp = WT + ((size_t)q * N + n0 + li) * 8;

    f32x4 acc[4];
    #pragma unroll
    for (int mt = 0; mt < 4; ++mt) acc[mt] = (f32x4){0.f, 0.f, 0.f, 0.f};
    #pragma unroll
    for (int ks = 0; ks < 8; ++ks) {
        bf16x8 bv = *(const bf16x8*)(bp + (size_t)ks * 32 * N);
        #pragma unroll
        for (int mt = 0; mt < 4; ++mt) {
            bf16x8 av = *(const bf16x8*)&xs[mt * 16 + li][ks * 32 + q * 8];
            acc[mt] = __builtin_amdgcn_mfma_f32_16x16x32_bf16(av, bv, acc[mt], 0, 0, 0);
        }
    }

    const int colg = n0 + li;
    const float bb = bias[colg];
    #pragma unroll
    for (int mt = 0; mt < 4; ++mt) {
        const int rbase = m0 + mt * 16 + q * 4;
        #pragma unroll
        for (int r = 0; r < 4; ++r) {
            const int row = rbase + r;
            float v = acc[mt][r] + bb;
            if constexpr (EPI == 0) {      // QKV -> bf16 attention layouts
                int b = row >> 10, l = row & 1023;
                int h = colg >> 5, d = colg & 31;
                int bh = b * HH + h;
                unsigned short* op = (unsigned short*)out;
                if (blockIdx.z == 0)
                    op[((size_t)bh * LL + l) * DD + d] = f2bf(v);
                else if (blockIdx.z == 1)
                    op[(size_t)bh * 32768 + (size_t)(d >> 3) * 8192 + (size_t)l * 8 + (d & 7)] = f2bf(v);
                else
                    op[(size_t)bh * 32768 + (size_t)(l >> 3) * 256 + (size_t)d * 8 + (l & 7)] = f2bf(v);
            } else {                        // gelu -> bf16
                ((unsigned short*)out)[(size_t)row * N + colg] = f2bf(gelu_f(v));
            }
        }
    }
}

// ---------------------------------------------------------------------------
// attn_part_mfma: flash attention partial over a 256-wide m-chunk, MFMA,
// zero barriers. Block = 256 thr (4 waves), wave = 16 q-rows.
// Grid (16 qt | 4 mc in x, H, B) = 1024 blocks.  (unchanged from R8)
// ---------------------------------------------------------------------------
__global__ __launch_bounds__(256, 4) void attn_part_mfma(
    const unsigned short* __restrict__ qb,
    const unsigned short* __restrict__ kswz,
    const unsigned short* __restrict__ vswz,
    const float* __restrict__ bias, const float* __restrict__ mask,
    const float* __restrict__ gate,
    float* __restrict__ Opart, float* __restrict__ statsM,
    float* __restrict__ statsL)
{
    __shared__ unsigned short Pbuf[4][16][72];
    const int t = threadIdx.x;
    const int wq = t >> 6, lane = t & 63;
    const int li = lane & 15, qd = lane >> 4;
    const int h = blockIdx.y, b = blockIdx.z;
    const int bh = b * HH + h;
    const int qt = blockIdx.x & 15, mc = blockIdx.x >> 4;
    const int q0 = qt * 64 + wq * 16;
    const int mbase = mc * 256;
    const float gh = gate[h];

    const bf16x8 qfrag = *(const bf16x8*)(qb + ((size_t)bh * LL + q0 + li) * DD + qd * 8);

    const unsigned short* kbase = kswz + (size_t)bh * 32768 + (size_t)qd * 8192 + (size_t)li * 8;
    const unsigned short* vbase = vswz + (size_t)bh * 32768 + (size_t)qd * 256 + (size_t)li * 8;
    const float* bp0 = bias + ((size_t)bh * LL + q0 + qd * 4) * LL + li;
    const float* mkp = mask + (size_t)b * LL + li;

    float mrun[4], lrun[4];
    f32x4 o0 = {0.f, 0.f, 0.f, 0.f}, o1 = {0.f, 0.f, 0.f, 0.f};
    #pragma unroll
    for (int r = 0; r < 4; ++r) { mrun[r] = -3.0e38f; lrun[r] = 0.f; }

    float bpre[4][4], kbpre[4];
    #pragma unroll
    for (int ms = 0; ms < 4; ++ms) {
        kbpre[ms] = mkp[mbase + ms * 16];
        #pragma unroll
        for (int r = 0; r < 4; ++r) bpre[ms][r] = bp0[(size_t)r * LL + mbase + ms * 16];
    }

    for (int mtt = 0; mtt < 4; ++mtt) {
        const int m0 = mbase + mtt * 64;
        f32x4 S[4];
        #pragma unroll
        for (int ms = 0; ms < 4; ++ms) {
            bf16x8 kf = *(const bf16x8*)(kbase + (size_t)(m0 + ms * 16) * 8);
            f32x4 z = {0.f, 0.f, 0.f, 0.f};
            S[ms] = __builtin_amdgcn_mfma_f32_16x16x32_bf16(qfrag, kf, z, 0, 0, 0);
        }
        float bc[4][4], kbc[4];
        #pragma unroll
        for (int ms = 0; ms < 4; ++ms) {
            kbc[ms] = (1.0f - kbpre[ms]) * (-10000.0f);
            #pragma unroll
            for (int r = 0; r < 4; ++r) bc[ms][r] = bpre[ms][r];
        }
        if (mtt < 3) {
            #pragma unroll
            for (int ms = 0; ms < 4; ++ms) {
                kbpre[ms] = mkp[m0 + 64 + ms * 16];
                #pragma unroll
                for (int r = 0; r < 4; ++r) bpre[ms][r] = bp0[(size_t)r * LL + m0 + 64 + ms * 16];
            }
        }
        float lg[4][4];
        #pragma unroll
        for (int ms = 0; ms < 4; ++ms)
            #pragma unroll
            for (int r = 0; r < 4; ++r)
                lg[ms][r] = fmaf(S[ms][r], SCALEF, fmaf(gh, bc[ms][r], kbc[ms]));

        float rmax[4];
        #pragma unroll
        for (int r = 0; r < 4; ++r)
            rmax[r] = fmaxf(fmaxf(lg[0][r], lg[1][r]), fmaxf(lg[2][r], lg[3][r]));
        #pragma unroll
        for (int bit = 1; bit < 16; bit <<= 1) {
            #pragma unroll
            for (int r = 0; r < 4; ++r) rmax[r] = fmaxf(rmax[r], __shfl_xor(rmax[r], bit, 64));
        }
        float alpha[4], rsum[4];
        #pragma unroll
        for (int r = 0; r < 4; ++r) {
            float nm = fmaxf(mrun[r], rmax[r]);
            alpha[r] = expf(mrun[r] - nm);
            mrun[r] = nm;
        }
        float p[4][4];
        #pragma unroll
        for (int r = 0; r < 4; ++r) rsum[r] = 0.f;
        #pragma unroll
        for (int ms = 0; ms < 4; ++ms)
            #pragma unroll
            for (int r = 0; r < 4; ++r) {
                p[ms][r] = expf(lg[ms][r] - mrun[r]);
                rsum[r] += p[ms][r];
            }
        #pragma unroll
        for (int bit = 1; bit < 16; bit <<= 1) {
            #pragma unroll
            for (int r = 0; r < 4; ++r) rsum[r] += __shfl_xor(rsum[r], bit, 64);
        }
        #pragma unroll
        for (int r = 0; r < 4; ++r) lrun[r] = lrun[r] * alpha[r] + rsum[r];
        #pragma unroll
        for (int r = 0; r < 4; ++r) { o0[r] *= alpha[r]; o1[r] *= alpha[r]; }
        #pragma unroll
        for (int ms = 0; ms < 4; ++ms)
            #pragma unroll
            for (int r = 0; r < 4; ++r)
                Pbuf[wq][qd * 4 + r][ms * 16 + li] = f2bf(p[ms][r]);
        #pragma unroll
        for (int c = 0; c < 2; ++c) {
            bf16x8 pa = *(const bf16x8*)&Pbuf[wq][li][c * 32 + qd * 8];
            bf16x8 vf0 = *(const bf16x8*)(vbase + (size_t)((m0 >> 3) + c * 4) * 256);
            bf16x8 vf1 = *(const bf16x8*)(vbase + (size_t)((m0 >> 3) + c * 4) * 256 + 16 * 8);
            o0 = __builtin_amdgcn_mfma_f32_16x16x32_bf16(pa, vf0, o0, 0, 0, 0);
            o1 = __builtin_amdgcn_mfma_f32_16x16x32_bf16(pa, vf1, o1, 0, 0, 0);
        }
    }
    const size_t rowg0 = (size_t)(mc * 2 + b) * LL;
    #pragma unroll
    for (int r = 0; r < 4; ++r) {
        const int row = q0 + qd * 4 + r;
        const size_t rg = rowg0 + row;
        Opart[rg * EE + h * DD + li]      = o0[r];
        Opart[rg * EE + h * DD + 16 + li] = o1[r];
        if (li == 0) {
            statsM[rg * HH + h] = mrun[r];
            statsL[rg * HH + h] = lrun[r];
        }
    }
}

// ---------------------------------------------------------------------------
// attn_merge: combine 4 m-chunk partials -> aob bf16 [2048][256]
// ---------------------------------------------------------------------------
__global__ __launch_bounds__(256) void attn_merge(
    const float* __restrict__ Opart, const float* __restrict__ statsM,
    const float* __restrict__ statsL, const float* __restrict__ mask,
    unsigned short* __restrict__ aob)
{
    const int row = blockIdx.x;
    const int e = threadIdx.x;
    const int h = e >> 5;
    float m_[4];
    float M = -3.0e38f;
    #pragma unroll
    for (int mc = 0; mc < 4; ++mc) {
        m_[mc] = statsM[((size_t)mc * 2048 + row) * HH + h];
        M = fmaxf(M, m_[mc]);
    }
    float Lsum = 0.f, V = 0.f;
    #pragma unroll
    for (int mc = 0; mc < 4; ++mc) {
        float sc = expf(m_[mc] - M);
        Lsum = fmaf(statsL[((size_t)mc * 2048 + row) * HH + h], sc, Lsum);
        V = fmaf(Opart[((size_t)mc * 2048 + row) * EE + e], sc, V);
    }
    const float mq = mask[row];
    const float r = (Lsum > 0.f ? V / Lsum : 0.f) * mq * mq;
    aob[(size_t)row * EE + e] = f2bf(r);
}

// ---------------------------------------------------------------------------
// pool_head: masked mean pool + LN + gelu(W1) + W2, one 1024-thr block per b.
// ---------------------------------------------------------------------------
__global__ __launch_bounds__(1024) void pool_head(
    const float* __restrict__ x, const float* __restrict__ mask,
    const float* __restrict__ hg, const float* __restrict__ hb,
    const float* __restrict__ w1, const float* __restrict__ b1,
    const float* __restrict__ w2, const float* __restrict__ b2,
    float* __restrict__ outp)
{
    __shared__ float psum[4][EE];
    __shared__ float msums[4];
    __shared__ float red[4];
    __shared__ float wred[4][NCN];
    __shared__ float pn[EE];
    const int b = blockIdx.x;
    const int t = threadIdx.x;
    const int col = t & 255, c = t >> 8;

    float s = 0.f, ms = 0.f;
    for (int i = 0; i < 256; ++i) {
        int l = c * 256 + i;
        float mm = mask[b * LL + l];
        s = fmaf(x[((size_t)b * LL + l) * EE + col], mm, s);
        ms += mm;
    }
    psum[c][col] = s;
    if (col == 0) msums[c] = ms;
    __syncthreads();

    float v = 0.f;
    const int wv = t >> 6, lane = t & 63;
    if (t < EE) {
        float tot = psum[0][t] + psum[1][t] + psum[2][t] + psum[3][t];
        float msum = msums[0] + msums[1] + msums[2] + msums[3];
        v = tot / fmaxf(msum, 1.0f);
        float sv = v;
        #pragma unroll
        for (int mm = 1; mm < 64; mm <<= 1) sv += __shfl_xor(sv, mm, 64);
        if (lane == 0) red[wv] = sv;
    }
    __syncthreads();
    const float mu = (red[0] + red[1] + red[2] + red[3]) * (1.0f / 256.0f);
    __syncthreads();
    if (t < EE) {
        float d = v - mu;
        float q2 = d * d;
        #pragma unroll
        for (int mm = 1; mm < 64; mm <<= 1) q2 += __shfl_xor(q2, mm, 64);
        if (lane == 0) red[wv] = q2;
    }
    __syncthreads();
    const float var = (red[0] + red[1] + red[2] + red[3]) * (1.0f / 256.0f);
    const float rstd = rsqrtf(var + 1e-5f);
    if (t < EE) pn[t] = (v - mu) * rstd * hg[t] + hb[t];
    __syncthreads();
    if (t < EE) {
        float acc = b1[t];
        #pragma unroll 8
        for (int k = 0; k < EE; ++k) acc = fmaf(pn[k], w1[k * EE + t], acc);
        const float g = gelu_f(acc);
        float contrib[NCN];
        #pragma unroll
        for (int cc = 0; cc < NCN; ++cc) contrib[cc] = g * w2[(size_t)t * NCN + cc];
        #pragma unroll
        for (int mm = 1; mm < 64; mm <<= 1) {
            #pragma unroll
            for (int cc = 0; cc < NCN; ++cc) contrib[cc] += __shfl_xor(contrib[cc], mm, 64);
        }
        if (lane == 0) {
            #pragma unroll
            for (int cc = 0; cc < NCN; ++cc) wred[wv][cc] = contrib[cc];
        }
    }
    __syncthreads();
    if (t < NCN)
        outp[b * NCN + t] = b2[t] + wred[0][t] + wred[1][t] + wred[2][t] + wred[3][t];
}

// ---------------------------------------------------------------------------
extern "C" void kernel_launch(void* const* d_in, const int* in_sizes, int n_in,
                              void* d_out, int out_size, void* d_ws, size_t ws_size,
                              hipStream_t stream) {
    const int*   tokens = (const int*)  d_in[0];
    const float* xp     = (const float*)d_in[1];
    const float* bias   = (const float*)d_in[2];
    const float* mask   = (const float*)d_in[3];
    const float* temb   = (const float*)d_in[4];
    const float* pe     = (const float*)d_in[5];
    const float* pw1    = (const float*)d_in[6];
    const float* pb1    = (const float*)d_in[7];
    const float* pw2    = (const float*)d_in[8];
    const float* pb2    = (const float*)d_in[9];
    const float* ln1g   = (const float*)d_in[10];
    const float* ln1b   = (const float*)d_in[11];
    const float* wq     = (const float*)d_in[12];
    const float* wk     = (const float*)d_in[13];
    const float* wv     = (const float*)d_in[14];
    const float* wo     = (const float*)d_in[15];
    const float* bq     = (const float*)d_in[16];
    const float* bk     = (const float*)d_in[17];
    const float* bv     = (const float*)d_in[18];
    const float* bo     = (const float*)d_in[19];
    const float* gate   = (const float*)d_in[20];
    const float* ln2g   = (const float*)d_in[21];
    const float* ln2b   = (const float*)d_in[22];
    const float* fw1    = (const float*)d_in[23];
    const float* fb1    = (const float*)d_in[24];
    const float* fw2    = (const float*)d_in[25];
    const float* fb2    = (const float*)d_in[26];
    const float* hlng   = (const float*)d_in[27];
    const float* hlnb   = (const float*)d_in[28];
    const float* hw1    = (const float*)d_in[29];
    const float* hb1    = (const float*)d_in[30];
    const float* hw2    = (const float*)d_in[31];
    const float* hb2    = (const float*)d_in[32];

    // ------ workspace layout ------
    float* ws = (float*)d_ws;
    const size_t NTOK = (size_t)BB * LL * EE;                 // 524288
    float* x      = ws;                                       // fp32 [2048][256]
    float* Opart  = ws + NTOK;                                // fp32 [4][2048][256]
    float* statsM = Opart + 4 * NTOK;                         // [4][2048][8]
    float* statsL = statsM + 65536;
    unsigned short* usp = (unsigned short*)(statsL + 65536);
    usp = (unsigned short*)(((size_t)usp + 15) & ~(size_t)15);
    unsigned short* qb16 = usp;                               // bf16 [BH][L][32]
    unsigned short* kswz = qb16 + NTOK;                       // bf16 [BH][4][1024][8]
    unsigned short* vswz = kswz + NTOK;                       // bf16 [BH][128][32][8]
    unsigned short* aob  = vswz + NTOK;                       // bf16 [2048][256]
    unsigned short* ffh  = aob + NTOK;                        // bf16 [2048][512]
    unsigned short* ph   = ffh + (size_t)BB * LL * HIDN;      // bf16 [2048][256]
    unsigned short* flat = ph + NTOK;                         // bf16 [2048][1056]
    unsigned short* wt   = flat + (size_t)BB * LL * KP1;      // weight pool

    // weight-pool sub-offsets (ushort units)
    const size_t OFF_PW1 = 0;                         // 1056*256 = 270336
    const size_t OFF_PW2 = 270336;                    // 65536
    const size_t OFF_QKVO = 335872;                   // 8 * 65536
    const size_t OFF_FW1 = 860160;                    // 2 * 131072
    const size_t OFF_FW2 = 1122304;                   // 2 * 131072

    // ------ prep descriptors ------
    PrepDesc pd;
    pd.src[0] = pw1;  pd.K[0] = INPAIR; pd.N[0] = EE;  pd.dst[0] = OFF_PW1;
    pd.src[1] = pw2;  pd.K[1] = EE;     pd.N[1] = EE;  pd.dst[1] = OFF_PW2;
    for (int l = 0; l < 2; ++l) {
        const float* srcs[4] = {wq + l * EE * EE, wk + l * EE * EE,
                                wv + l * EE * EE, wo + l * EE * EE};
        for (int wch = 0; wch < 4; ++wch) {
            int mi = 2 + l * 4 + wch;
            pd.src[mi] = srcs[wch]; pd.K[mi] = EE; pd.N[mi] = EE;
            pd.dst[mi] = OFF_QKVO + (size_t)(l * 4 + wch) * 65536;
        }
    }
    for (int l = 0; l < 2; ++l) {
        pd.src[10 + l] = fw1 + (size_t)l * EE * HIDN;
        pd.K[10 + l] = EE;  pd.N[10 + l] = HIDN;
        pd.dst[10 + l] = OFF_FW1 + (size_t)l * 131072;
        pd.src[12 + l] = fw2 + (size_t)l * HIDN * EE;
        pd.K[12 + l] = HIDN; pd.N[12 + l] = EE;
        pd.dst[12 + l] = OFF_FW2 + (size_t)l * 131072;
    }

    // ------ weight prep + pairwise gather (one launch) ------
    prep_gather<<<dim3(1848 + 2048), dim3(256), 0, stream>>>(pd, wt, xp, flat);

    // MLP1: relu(flat @ w1 + b1) -> ph (bf16)
    gemm_mfma<KP1, 3><<<dim3(32, 16, 1), dim3(256), 0, stream>>>(
        flat, wt + OFF_PW1, pb1, ph, nullptr, nullptr, nullptr,
        nullptr, nullptr, nullptr, EE, nullptr, nullptr, nullptr);
    // MLP2: ph @ w2 + b2 + temb + pe -> x (fp32)
    gemm_mfma<EE, 4><<<dim3(32, 16, 1), dim3(256), 0, stream>>>(
        ph, wt + OFF_PW2, pb2, x, nullptr, nullptr, nullptr,
        nullptr, nullptr, nullptr, EE, tokens, temb, pe);

    for (int i = 0; i < NLAYER; ++i) {
        // QKV with LN1 fused (one launch, z = 3) -> bf16 attention layouts
        gemm_ln_mfma<0><<<dim3(32, 4, 3), dim3(256), 0, stream>>>(
            x, ln1g + i * EE, ln1b + i * EE,
            wt + OFF_QKVO + (size_t)(i * 4 + 0) * 65536, bq + i * EE, qb16,
            wt + OFF_QKVO + (size_t)(i * 4 + 1) * 65536, bk + i * EE, kswz,
            wt + OFF_QKVO + (size_t)(i * 4 + 2) * 65536, bv + i * EE, vswz,
            EE);
        // flash attention partials (m-split x4) + merge -> aob bf16
        attn_part_mfma<<<dim3(64, HH, BB), dim3(256), 0, stream>>>(
            qb16, kswz, vswz, bias, mask, gate + i * HH, Opart, statsM, statsL);
        attn_merge<<<dim3(2048), dim3(256), 0, stream>>>(Opart, statsM, statsL, mask, aob);
        // O-proj + residual: x += aob @ wo + bo
        gemm_mfma<EE, 1><<<dim3(32, 16, 1), dim3(256), 0, stream>>>(
            aob, wt + OFF_QKVO + (size_t)(i * 4 + 3) * 65536, bo + i * EE, x,
            nullptr, nullptr, nullptr, nullptr, nullptr, nullptr,
            EE, nullptr, nullptr, nullptr);
        // FFN1 with LN2 fused: gelu(LN(x) @ fw1 + fb1) -> ffh (bf16)
        gemm_ln_mfma<2><<<dim3(32, 8, 1), dim3(256), 0, stream>>>(
            x, ln2g + i * EE, ln2b + i * EE,
            wt + OFF_FW1 + (size_t)i * 131072, fb1 + i * HIDN, ffh,
            nullptr, nullptr, nullptr, nullptr, nullptr, nullptr,
            HIDN);
        // FFN2: x += ffh @ fw2 + fb2
        gemm_mfma<HIDN, 1><<<dim3(32, 16, 1), dim3(256), 0, stream>>>(
            ffh, wt + OFF_FW2 + (size_t)i * 131072, fb2 + i * EE, x,
            nullptr, nullptr, nullptr, nullptr, nullptr, nullptr,
            EE, nullptr, nullptr, nullptr);
    }

    pool_head<<<dim3(BB), dim3(1024), 0, stream>>>(
        x, mask, hlng, hlnb, hw1, hb1, hw2, hb2, (float*)d_out);

    (void)in_sizes; (void)n_in; (void)out_size; (void)ws_size;
}

// Round 10
// 330.764 us; speedup vs baseline: 1.0562x; 1.0562x over previous
//
#include <hip/hip_runtime.h>
#include <math.h>

// Problem constants (fixed by the reference)
#define BB     2
#define LL     1024
#define CC     4
#define EE     256
#define HH     8
#define DD     32
#define NLAYER 2
#define W1N    257          // WIN+1
#define INPAIR 1028         // C*(WIN+1)
#define KP1    1056         // INPAIR padded to 32
#define HIDN   512
#define NCN    10
#define SCALEF 0.17677669529663687f   // 32^-0.5

typedef short bf16x8 __attribute__((ext_vector_type(8)));
typedef float f32x4  __attribute__((ext_vector_type(4)));
typedef unsigned short u16x4 __attribute__((ext_vector_type(4)));
typedef unsigned short u16x8 __attribute__((ext_vector_type(8)));

__device__ __forceinline__ float gelu_f(float x) {
    return 0.5f * x * (1.0f + erff(x * 0.7071067811865475f));
}
__device__ __forceinline__ unsigned short f2bf(float f) {
    unsigned u = __float_as_uint(f);
    u += 0x7fffu + ((u >> 16) & 1u);      // RNE
    return (unsigned short)(u >> 16);
}

// ---------------------------------------------------------------------------
// prep_gather: one launch for both weight conversion and the pairwise gather.
// ---------------------------------------------------------------------------
struct PrepDesc {
    const float* src[14];
    int K[14];
    int N[14];
    unsigned long long dst[14];
};

__global__ __launch_bounds__(256) void prep_gather(
    PrepDesc pd, unsigned short* __restrict__ wt,
    const float* __restrict__ xp, unsigned short* __restrict__ flat)
{
    const int bid = blockIdx.x;
    if (bid < 1848) {
        const int mi = bid / 132, k8 = bid - mi * 132;
        const int K = pd.K[mi], N = pd.N[mi];
        const int Kp = (K + 31) & ~31;
        if (k8 * 8 >= Kp) return;
        const float* src = pd.src[mi];
        unsigned short* dst = wt + pd.dst[mi];
        for (int n = threadIdx.x; n < N; n += 256) {
            u16x8 o;
            #pragma unroll
            for (int j = 0; j < 8; ++j) {
                int k = k8 * 8 + j;
                float v = (k < K) ? src[(size_t)k * N + n] : 0.f;
                o[j] = f2bf(v);
            }
            *(u16x8*)(dst + ((size_t)k8 * N + n) * 8) = o;
        }
    } else {
        const int row = bid - 1848;
        const int b = row >> 10, l = row & 1023;
        const float* base = xp + (size_t)b * CC * LL * LL + (size_t)l * LL;
        for (int kp = threadIdx.x; kp < KP1; kp += 256) {
            float v = 0.f;
            if (kp < INPAIR) {
                int c = kp / W1N;
                int w = kp - c * W1N;
                int col = l + w - 128;
                if (col >= 0 && col < LL) v = base[(size_t)c * LL * LL + col];
            }
            flat[(size_t)row * KP1 + kp] = f2bf(v);
        }
    }
}

// ---------------------------------------------------------------------------
// ln_bf16: per-row LayerNorm of fp32 x -> bf16 out. 1 wave per row.
// ---------------------------------------------------------------------------
__global__ __launch_bounds__(256) void ln_bf16(
    const float* __restrict__ x, const float* __restrict__ g,
    const float* __restrict__ bt, unsigned short* __restrict__ out)
{
    const int row = blockIdx.x * 4 + (threadIdx.x >> 6);
    const int lane = threadIdx.x & 63;
    float4 v = *(const float4*)(x + (size_t)row * EE + lane * 4);
    float s = v.x + v.y + v.z + v.w;
    #pragma unroll
    for (int m = 1; m < 64; m <<= 1) s += __shfl_xor(s, m, 64);
    const float mu = s * (1.0f / 256.0f);
    float q2 = 0.f, d;
    d = v.x - mu; q2 += d * d; d = v.y - mu; q2 += d * d;
    d = v.z - mu; q2 += d * d; d = v.w - mu; q2 += d * d;
    #pragma unroll
    for (int m = 1; m < 64; m <<= 1) q2 += __shfl_xor(q2, m, 64);
    const float rstd = rsqrtf(q2 * (1.0f / 256.0f) + 1e-5f);
    float4 gg = *(const float4*)(g + lane * 4);
    float4 bb = *(const float4*)(bt + lane * 4);
    u16x4 o;
    o[0] = f2bf((v.x - mu) * rstd * gg.x + bb.x);
    o[1] = f2bf((v.y - mu) * rstd * gg.y + bb.y);
    o[2] = f2bf((v.z - mu) * rstd * gg.z + bb.z);
    o[3] = f2bf((v.w - mu) * rstd * gg.w + bb.w);
    *(u16x4*)(out + (size_t)row * EE + lane * 4) = o;
}

// ---------------------------------------------------------------------------
// gemm_mfma: out = epi(A_bf16 @ W + bias). No LDS, no barriers. (R5/R8 proven)
// EPI: 0=QKV pack (z: 0=Q A-layout bf16, 1=K swz, 2=V swz)
//      1=residual +=, 2=gelu->bf16, 3=relu->bf16, 4=emb->fp32
// ---------------------------------------------------------------------------
template<int KP, int EPI>
__global__ __launch_bounds__(256) void gemm_mfma(
    const unsigned short* __restrict__ A,
    const unsigned short* wt0, const float* b0, void* o0,
    const unsigned short* wt1, const float* b1, void* o1,
    const unsigned short* wt2, const float* b2, void* o2,
    int N,
    const int* __restrict__ tokens, const float* __restrict__ temb,
    const float* __restrict__ pe)
{
    const int t = threadIdx.x;
    const int w = t >> 6, lane = t & 63;
    const int m0 = blockIdx.x * 64 + w * 16;
    const int n0 = blockIdx.y * 16;
    const unsigned short* WT; const float* bias; void* out;
    if (blockIdx.z == 0)      { WT = wt0; bias = b0; out = o0; }
    else if (blockIdx.z == 1) { WT = wt1; bias = b1; out = o1; }
    else                      { WT = wt2; bias = b2; out = o2; }

    const int q = lane >> 4, li = lane & 15;
    const unsigned short* ap = A + (size_t)(m0 + li) * KP + q * 8;
    const unsigned short* bp = WT + ((size_t)q * N + n0 + li) * 8;
    f32x4 acc = {0.f, 0.f, 0.f, 0.f};
    for (int ks = 0; ks < KP / 32; ++ks) {
        bf16x8 av = *(const bf16x8*)(ap + ks * 32);
        bf16x8 bv = *(const bf16x8*)(bp + (size_t)ks * 32 * N);
        acc = __builtin_amdgcn_mfma_f32_16x16x32_bf16(av, bv, acc, 0, 0, 0);
    }

    const int colg = n0 + li;
    const float bb = bias[colg];
    const int rbase = m0 + q * 4;
    #pragma unroll
    for (int r = 0; r < 4; ++r) {
        const int row = rbase + r;
        float v = acc[r] + bb;
        if constexpr (EPI == 0) {          // QKV -> bf16 attention layouts
            int b = row >> 10, l = row & 1023;
            int h = colg >> 5, d = colg & 31;
            int bh = b * HH + h;
            unsigned short* op = (unsigned short*)out;
            if (blockIdx.z == 0)
                op[((size_t)bh * LL + l) * DD + d] = f2bf(v);
            else if (blockIdx.z == 1)
                op[(size_t)bh * 32768 + (size_t)(d >> 3) * 8192 + (size_t)l * 8 + (d & 7)] = f2bf(v);
            else
                op[(size_t)bh * 32768 + (size_t)(l >> 3) * 256 + (size_t)d * 8 + (l & 7)] = f2bf(v);
        } else if constexpr (EPI == 1) {   // residual accumulate into fp32 out
            float* op = (float*)out;
            op[(size_t)row * N + colg] += v;
        } else if constexpr (EPI == 2) {   // gelu -> bf16
            ((unsigned short*)out)[(size_t)row * N + colg] = f2bf(gelu_f(v));
        } else if constexpr (EPI == 3) {   // relu -> bf16
            ((unsigned short*)out)[(size_t)row * N + colg] = f2bf(fmaxf(v, 0.f));
        } else {                            // emb: + temb[tok] + pe -> fp32
            int tok = tokens[row];
            v += temb[(size_t)tok * EE + colg] + pe[(size_t)(row & 1023) * EE + colg];
            ((float*)out)[(size_t)row * EE + colg] = v;
        }
    }
}

// ---------------------------------------------------------------------------
// attn_part_mfma (R10): flash attention partial, MFMA, zero block barriers.
// NEW row-per-lane softmax: S round-trips LDS (per-wave, fp32); each lane
// then owns ONE q-row (li) x 16 m-cols (qd*8+j / 32+qd*8+j), so bias loads
// are 4x float4 (128B bursts) and P stays in registers in A-layout.
// Block = 256 thr (4 waves), wave = 16 q-rows. Grid (16 qt | 4 mc, H, B).
// ---------------------------------------------------------------------------
__global__ __launch_bounds__(256, 4) void attn_part_mfma(
    const unsigned short* __restrict__ qb,
    const unsigned short* __restrict__ kswz,
    const unsigned short* __restrict__ vswz,
    const float* __restrict__ bias, const float* __restrict__ mask,
    const float* __restrict__ gate,
    float* __restrict__ Opart, float* __restrict__ statsM,
    float* __restrict__ statsL)
{
    __shared__ float Sbuf[4][16][68];     // per-wave S tile [q-row][m-col] (+4 pad)
    const int t = threadIdx.x;
    const int wq = t >> 6, lane = t & 63;
    const int li = lane & 15, qd = lane >> 4;
    const int h = blockIdx.y, b = blockIdx.z;
    const int bh = b * HH + h;
    const int qt = blockIdx.x & 15, mc = blockIdx.x >> 4;
    const int q0 = qt * 64 + wq * 16;
    const int mbase = mc * 256;
    const float gh = gate[h];

    const bf16x8 qfrag = *(const bf16x8*)(qb + ((size_t)bh * LL + q0 + li) * DD + qd * 8);
    const unsigned short* kbase = kswz + (size_t)bh * 32768 + (size_t)qd * 8192 + (size_t)li * 8;
    const unsigned short* vbase = vswz + (size_t)bh * 32768 + (size_t)qd * 256 + (size_t)li * 8;
    // this lane's softmax row (q0+li) bias pointer; cols offset by qd*8
    const float* brow = bias + ((size_t)bh * LL + q0 + li) * LL;
    const float* mrow = mask + (size_t)b * LL;

    float mrun = -3.0e38f, lrun = 0.f;    // for q-row (q0+li), replicated over qd
    f32x4 o0 = {0.f, 0.f, 0.f, 0.f}, o1 = {0.f, 0.f, 0.f, 0.f};

    for (int mtt = 0; mtt < 4; ++mtt) {
        const int m0 = mbase + mtt * 64;
        // ---- bias + mask loads for THIS lane's row, 128B-coalesced ----
        float4 bv0 = *(const float4*)(brow + m0 + qd * 8);
        float4 bv1 = *(const float4*)(brow + m0 + qd * 8 + 4);
        float4 bv2 = *(const float4*)(brow + m0 + 32 + qd * 8);
        float4 bv3 = *(const float4*)(brow + m0 + 32 + qd * 8 + 4);
        float4 mk0 = *(const float4*)(mrow + m0 + qd * 8);
        float4 mk1 = *(const float4*)(mrow + m0 + qd * 8 + 4);
        float4 mk2 = *(const float4*)(mrow + m0 + 32 + qd * 8);
        float4 mk3 = *(const float4*)(mrow + m0 + 32 + qd * 8 + 4);
        // ---- S = Q K^T (C-layout) ----
        f32x4 S[4];
        #pragma unroll
        for (int ms = 0; ms < 4; ++ms) {
            bf16x8 kf = *(const bf16x8*)(kbase + (size_t)(m0 + ms * 16) * 8);
            f32x4 z = {0.f, 0.f, 0.f, 0.f};
            S[ms] = __builtin_amdgcn_mfma_f32_16x16x32_bf16(qfrag, kf, z, 0, 0, 0);
        }
        // ---- S -> LDS (C-layout write; same-wave RAW, no barrier) ----
        #pragma unroll
        for (int ms = 0; ms < 4; ++ms)
            #pragma unroll
            for (int r = 0; r < 4; ++r)
                Sbuf[wq][qd * 4 + r][ms * 16 + li] = S[ms][r];
        // ---- read S row-per-lane: row li, cols qd*8+{0..7}, 32+qd*8+{0..7} ----
        float4 s0 = *(const float4*)&Sbuf[wq][li][qd * 8];
        float4 s1 = *(const float4*)&Sbuf[wq][li][qd * 8 + 4];
        float4 s2 = *(const float4*)&Sbuf[wq][li][32 + qd * 8];
        float4 s3 = *(const float4*)&Sbuf[wq][li][32 + qd * 8 + 4];
        // ---- logits ----
        float lg[16];
        lg[0]  = fmaf(s0.x, SCALEF, fmaf(gh, bv0.x, (1.0f - mk0.x) * -10000.0f));
        lg[1]  = fmaf(s0.y, SCALEF, fmaf(gh, bv0.y, (1.0f - mk0.y) * -10000.0f));
        lg[2]  = fmaf(s0.z, SCALEF, fmaf(gh, bv0.z, (1.0f - mk0.z) * -10000.0f));
        lg[3]  = fmaf(s0.w, SCALEF, fmaf(gh, bv0.w, (1.0f - mk0.w) * -10000.0f));
        lg[4]  = fmaf(s1.x, SCALEF, fmaf(gh, bv1.x, (1.0f - mk1.x) * -10000.0f));
        lg[5]  = fmaf(s1.y, SCALEF, fmaf(gh, bv1.y, (1.0f - mk1.y) * -10000.0f));
        lg[6]  = fmaf(s1.z, SCALEF, fmaf(gh, bv1.z, (1.0f - mk1.z) * -10000.0f));
        lg[7]  = fmaf(s1.w, SCALEF, fmaf(gh, bv1.w, (1.0f - mk1.w) * -10000.0f));
        lg[8]  = fmaf(s2.x, SCALEF, fmaf(gh, bv2.x, (1.0f - mk2.x) * -10000.0f));
        lg[9]  = fmaf(s2.y, SCALEF, fmaf(gh, bv2.y, (1.0f - mk2.y) * -10000.0f));
        lg[10] = fmaf(s2.z, SCALEF, fmaf(gh, bv2.z, (1.0f - mk2.z) * -10000.0f));
        lg[11] = fmaf(s2.w, SCALEF, fmaf(gh, bv2.w, (1.0f - mk2.w) * -10000.0f));
        lg[12] = fmaf(s3.x, SCALEF, fmaf(gh, bv3.x, (1.0f - mk3.x) * -10000.0f));
        lg[13] = fmaf(s3.y, SCALEF, fmaf(gh, bv3.y, (1.0f - mk3.y) * -10000.0f));
        lg[14] = fmaf(s3.z, SCALEF, fmaf(gh, bv3.z, (1.0f - mk3.z) * -10000.0f));
        lg[15] = fmaf(s3.w, SCALEF, fmaf(gh, bv3.w, (1.0f - mk3.w) * -10000.0f));
        // ---- online softmax (row li lives in 4 lanes: xor 16, 32) ----
        float tm = lg[0];
        #pragma unroll
        for (int j = 1; j < 16; ++j) tm = fmaxf(tm, lg[j]);
        tm = fmaxf(tm, __shfl_xor(tm, 16, 64));
        tm = fmaxf(tm, __shfl_xor(tm, 32, 64));
        const float nm = fmaxf(mrun, tm);
        const float alpha = expf(mrun - nm);
        mrun = nm;
        float p[16];
        float ts = 0.f;
        #pragma unroll
        for (int j = 0; j < 16; ++j) { p[j] = expf(lg[j] - nm); ts += p[j]; }
        ts += __shfl_xor(ts, 16, 64);
        ts += __shfl_xor(ts, 32, 64);
        lrun = lrun * alpha + ts;
        // ---- rescale O (rows qd*4+r): fetch those rows' alpha ----
        #pragma unroll
        for (int r = 0; r < 4; ++r) {
            const float al = __shfl(alpha, qd * 4 + r, 64);
            o0[r] *= al; o1[r] *= al;
        }
        // ---- P already in A-layout: pack and multiply-accumulate with V ----
        u16x8 pu0, pu1;
        #pragma unroll
        for (int j = 0; j < 8; ++j) { pu0[j] = f2bf(p[j]); pu1[j] = f2bf(p[8 + j]); }
        const bf16x8 pa0 = *(bf16x8*)&pu0;
        const bf16x8 pa1 = *(bf16x8*)&pu1;
        {
            const unsigned short* v0p = vbase + (size_t)((m0 >> 3) + 0) * 256;
            const unsigned short* v1p = vbase + (size_t)((m0 >> 3) + 4) * 256;
            bf16x8 vf00 = *(const bf16x8*)(v0p);
            bf16x8 vf01 = *(const bf16x8*)(v0p + 16 * 8);
            bf16x8 vf10 = *(const bf16x8*)(v1p);
            bf16x8 vf11 = *(const bf16x8*)(v1p + 16 * 8);
            o0 = __builtin_amdgcn_mfma_f32_16x16x32_bf16(pa0, vf00, o0, 0, 0, 0);
            o1 = __builtin_amdgcn_mfma_f32_16x16x32_bf16(pa0, vf01, o1, 0, 0, 0);
            o0 = __builtin_amdgcn_mfma_f32_16x16x32_bf16(pa1, vf10, o0, 0, 0, 0);
            o1 = __builtin_amdgcn_mfma_f32_16x16x32_bf16(pa1, vf11, o1, 0, 0, 0);
        }
    }
    // ---- write partial O (fp32, unnormalized) + per-row stats ----
    const size_t rowg0 = (size_t)(mc * 2 + b) * LL;
    #pragma unroll
    for (int r = 0; r < 4; ++r) {
        const int row = q0 + qd * 4 + r;
        const size_t rg = rowg0 + row;
        Opart[rg * EE + h * DD + li]      = o0[r];
        Opart[rg * EE + h * DD + 16 + li] = o1[r];
    }
    if (qd == 0) {
        const size_t rg = rowg0 + q0 + li;
        statsM[rg * HH + h] = mrun;
        statsL[rg * HH + h] = lrun;
    }
}

// ---------------------------------------------------------------------------
// attn_merge: combine 4 m-chunk partials -> aob bf16 [2048][256]
// ---------------------------------------------------------------------------
__global__ __launch_bounds__(256) void attn_merge(
    const float* __restrict__ Opart, const float* __restrict__ statsM,
    const float* __restrict__ statsL, const float* __restrict__ mask,
    unsigned short* __restrict__ aob)
{
    const int row = blockIdx.x;
    const int e = threadIdx.x;
    const int h = e >> 5;
    float m_[4];
    float M = -3.0e38f;
    #pragma unroll
    for (int mc = 0; mc < 4; ++mc) {
        m_[mc] = statsM[((size_t)mc * 2048 + row) * HH + h];
        M = fmaxf(M, m_[mc]);
    }
    float Lsum = 0.f, V = 0.f;
    #pragma unroll
    for (int mc = 0; mc < 4; ++mc) {
        float sc = expf(m_[mc] - M);
        Lsum = fmaf(statsL[((size_t)mc * 2048 + row) * HH + h], sc, Lsum);
        V = fmaf(Opart[((size_t)mc * 2048 + row) * EE + e], sc, V);
    }
    const float mq = mask[row];
    const float r = (Lsum > 0.f ? V / Lsum : 0.f) * mq * mq;
    aob[(size_t)row * EE + e] = f2bf(r);
}

// ---------------------------------------------------------------------------
// pool stage 1: partial sums over 64-row chunks (R5 proven)
// ---------------------------------------------------------------------------
__global__ __launch_bounds__(256) void pool_part(
    const float* __restrict__ x, const float* __restrict__ mask,
    float* __restrict__ part, float* __restrict__ pmask)
{
    const int ch = blockIdx.x, b = blockIdx.y, t = threadIdx.x;
    const int l0 = ch * 64;
    float s = 0.f, ms = 0.f;
    #pragma unroll 4
    for (int i = 0; i < 64; ++i) {
        int l = l0 + i;
        float mm = mask[b * LL + l];
        s = fmaf(x[((size_t)(b * LL + l)) * EE + t], mm, s);
        ms += mm;
    }
    part[(size_t)(b * 16 + ch) * EE + t] = s;
    if (t == 0) pmask[b * 16 + ch] = ms;
}

// ---------------------------------------------------------------------------
// head: pool-reduce + LN + gelu(W1) + W2, one block per batch element (R5)
// ---------------------------------------------------------------------------
__global__ __launch_bounds__(256) void head_kernel(
    const float* __restrict__ part, const float* __restrict__ pmask,
    const float* __restrict__ hg, const float* __restrict__ hb,
    const float* __restrict__ w1, const float* __restrict__ b1,
    const float* __restrict__ w2, const float* __restrict__ b2,
    float* __restrict__ outp)
{
    __shared__ float pn[EE];
    __shared__ float red[4];
    __shared__ float wred[4][NCN];
    const int b = blockIdx.x;
    const int t = threadIdx.x;
    const int wv = t >> 6, lane = t & 63;

    float v = 0.f, msum = 0.f;
    #pragma unroll
    for (int c = 0; c < 16; ++c) {
        v += part[(size_t)(b * 16 + c) * EE + t];
        msum += pmask[b * 16 + c];
    }
    v = v / fmaxf(msum, 1.0f);
    float s = v;
    #pragma unroll
    for (int mm = 1; mm < 64; mm <<= 1) s += __shfl_xor(s, mm, 64);
    if (lane == 0) red[wv] = s;
    __syncthreads();
    const float mu = (red[0] + red[1] + red[2] + red[3]) * (1.0f / 256.0f);
    __syncthreads();
    float d = v - mu;
    float q2 = d * d;
    #pragma unroll
    for (int mm = 1; mm < 64; mm <<= 1) q2 += __shfl_xor(q2, mm, 64);
    if (lane == 0) red[wv] = q2;
    __syncthreads();
    const float var = (red[0] + red[1] + red[2] + red[3]) * (1.0f / 256.0f);
    const float rstd = rsqrtf(var + 1e-5f);
    pn[t] = d * rstd * hg[t] + hb[t];
    __syncthreads();
    float acc = b1[t];
    #pragma unroll 8
    for (int k = 0; k < EE; ++k) acc = fmaf(pn[k], w1[k * EE + t], acc);
    const float g = gelu_f(acc);
    float contrib[NCN];
    #pragma unroll
    for (int c = 0; c < NCN; ++c) contrib[c] = g * w2[(size_t)t * NCN + c];
    #pragma unroll
    for (int mm = 1; mm < 64; mm <<= 1) {
        #pragma unroll
        for (int c = 0; c < NCN; ++c) contrib[c] += __shfl_xor(contrib[c], mm, 64);
    }
    if (lane == 0) {
        #pragma unroll
        for (int c = 0; c < NCN; ++c) wred[wv][c] = contrib[c];
    }
    __syncthreads();
    if (t < NCN)
        outp[b * NCN + t] = b2[t] + wred[0][t] + wred[1][t] + wred[2][t] + wred[3][t];
}

// ---------------------------------------------------------------------------
extern "C" void kernel_launch(void* const* d_in, const int* in_sizes, int n_in,
                              void* d_out, int out_size, void* d_ws, size_t ws_size,
                              hipStream_t stream) {
    const int*   tokens = (const int*)  d_in[0];
    const float* xp     = (const float*)d_in[1];
    const float* bias   = (const float*)d_in[2];
    const float* mask   = (const float*)d_in[3];
    const float* temb   = (const float*)d_in[4];
    const float* pe     = (const float*)d_in[5];
    const float* pw1    = (const float*)d_in[6];
    const float* pb1    = (const float*)d_in[7];
    const float* pw2    = (const float*)d_in[8];
    const float* pb2    = (const float*)d_in[9];
    const float* ln1g   = (const float*)d_in[10];
    const float* ln1b   = (const float*)d_in[11];
    const float* wq     = (const float*)d_in[12];
    const float* wk     = (const float*)d_in[13];
    const float* wv     = (const float*)d_in[14];
    const float* wo     = (const float*)d_in[15];
    const float* bq     = (const float*)d_in[16];
    const float* bk     = (const float*)d_in[17];
    const float* bv     = (const float*)d_in[18];
    const float* bo     = (const float*)d_in[19];
    const float* gate   = (const float*)d_in[20];
    const float* ln2g   = (const float*)d_in[21];
    const float* ln2b   = (const float*)d_in[22];
    const float* fw1    = (const float*)d_in[23];
    const float* fb1    = (const float*)d_in[24];
    const float* fw2    = (const float*)d_in[25];
    const float* fb2    = (const float*)d_in[26];
    const float* hlng   = (const float*)d_in[27];
    const float* hlnb   = (const float*)d_in[28];
    const float* hw1    = (const float*)d_in[29];
    const float* hb1    = (const float*)d_in[30];
    const float* hw2    = (const float*)d_in[31];
    const float* hb2    = (const float*)d_in[32];

    // ------ workspace layout ------
    float* ws = (float*)d_ws;
    const size_t NTOK = (size_t)BB * LL * EE;                 // 524288
    float* x      = ws;                                       // fp32 [2048][256]
    float* Opart  = ws + NTOK;                                // fp32 [4][2048][256]
    float* statsM = Opart + 4 * NTOK;                         // [4][2048][8]
    float* statsL = statsM + 65536;
    float* part   = statsL + 65536;                           // [2][16][256]
    float* pmaskp = part + 32 * EE;                           // [32]
    unsigned short* usp = (unsigned short*)(pmaskp + 32);
    usp = (unsigned short*)(((size_t)usp + 15) & ~(size_t)15);
    unsigned short* qb16 = usp;                               // bf16 [BH][L][32]
    unsigned short* kswz = qb16 + NTOK;                       // bf16 [BH][4][1024][8]
    unsigned short* vswz = kswz + NTOK;                       // bf16 [BH][128][32][8]
    unsigned short* aob  = vswz + NTOK;                       // bf16 [2048][256]
    unsigned short* ffh  = aob + NTOK;                        // bf16 [2048][512]
    unsigned short* ph   = ffh + (size_t)BB * LL * HIDN;      // bf16 [2048][256] (xn alias)
    unsigned short* flat = ph + NTOK;                         // bf16 [2048][1056]
    unsigned short* wt   = flat + (size_t)BB * LL * KP1;      // weight pool

    // weight-pool sub-offsets (ushort units)
    const size_t OFF_PW1 = 0;                         // 1056*256 = 270336
    const size_t OFF_PW2 = 270336;                    // 65536
    const size_t OFF_QKVO = 335872;                   // 8 * 65536
    const size_t OFF_FW1 = 860160;                    // 2 * 131072
    const size_t OFF_FW2 = 1122304;                   // 2 * 131072

    // ------ prep descriptors ------
    PrepDesc pd;
    pd.src[0] = pw1;  pd.K[0] = INPAIR; pd.N[0] = EE;  pd.dst[0] = OFF_PW1;
    pd.src[1] = pw2;  pd.K[1] = EE;     pd.N[1] = EE;  pd.dst[1] = OFF_PW2;
    for (int l = 0; l < 2; ++l) {
        const float* srcs[4] = {wq + l * EE * EE, wk + l * EE * EE,
                                wv + l * EE * EE, wo + l * EE * EE};
        for (int wch = 0; wch < 4; ++wch) {
            int mi = 2 + l * 4 + wch;
            pd.src[mi] = srcs[wch]; pd.K[mi] = EE; pd.N[mi] = EE;
            pd.dst[mi] = OFF_QKVO + (size_t)(l * 4 + wch) * 65536;
        }
    }
    for (int l = 0; l < 2; ++l) {
        pd.src[10 + l] = fw1 + (size_t)l * EE * HIDN;
        pd.K[10 + l] = EE;  pd.N[10 + l] = HIDN;
        pd.dst[10 + l] = OFF_FW1 + (size_t)l * 131072;
        pd.src[12 + l] = fw2 + (size_t)l * HIDN * EE;
        pd.K[12 + l] = HIDN; pd.N[12 + l] = EE;
        pd.dst[12 + l] = OFF_FW2 + (size_t)l * 131072;
    }

    // ------ weight prep + pairwise gather (one launch) ------
    prep_gather<<<dim3(1848 + 2048), dim3(256), 0, stream>>>(pd, wt, xp, flat);

    // MLP1: relu(flat @ w1 + b1) -> ph (bf16)
    gemm_mfma<KP1, 3><<<dim3(32, 16, 1), dim3(256), 0, stream>>>(
        flat, wt + OFF_PW1, pb1, ph, nullptr, nullptr, nullptr,
        nullptr, nullptr, nullptr, EE, nullptr, nullptr, nullptr);
    // MLP2: ph @ w2 + b2 + temb + pe -> x (fp32)
    gemm_mfma<EE, 4><<<dim3(32, 16, 1), dim3(256), 0, stream>>>(
        ph, wt + OFF_PW2, pb2, x, nullptr, nullptr, nullptr,
        nullptr, nullptr, nullptr, EE, tokens, temb, pe);

    for (int i = 0; i < NLAYER; ++i) {
        unsigned short* xn = ph;   // ph dead after MLP2; reused as LN output
        // LN1 -> xn (bf16)
        ln_bf16<<<dim3(512), dim3(256), 0, stream>>>(x, ln1g + i * EE, ln1b + i * EE, xn);
        // QKV (one launch, z = 3) -> bf16 attention layouts
        gemm_mfma<EE, 0><<<dim3(32, 16, 3), dim3(256), 0, stream>>>(
            xn,
            wt + OFF_QKVO + (size_t)(i * 4 + 0) * 65536, bq + i * EE, qb16,
            wt + OFF_QKVO + (size_t)(i * 4 + 1) * 65536, bk + i * EE, kswz,
            wt + OFF_QKVO + (size_t)(i * 4 + 2) * 65536, bv + i * EE, vswz,
            EE, nullptr, nullptr, nullptr);
        // flash attention partials (m-split x4, coalesced bias) + merge
        attn_part_mfma<<<dim3(64, HH, BB), dim3(256), 0, stream>>>(
            qb16, kswz, vswz, bias, mask, gate + i * HH, Opart, statsM, statsL);
        attn_merge<<<dim3(2048), dim3(256), 0, stream>>>(Opart, statsM, statsL, mask, aob);
        // O-proj + residual: x += aob @ wo + bo
        gemm_mfma<EE, 1><<<dim3(32, 16, 1), dim3(256), 0, stream>>>(
            aob, wt + OFF_QKVO + (size_t)(i * 4 + 3) * 65536, bo + i * EE, x,
            nullptr, nullptr, nullptr, nullptr, nullptr, nullptr,
            EE, nullptr, nullptr, nullptr);
        // LN2 -> xn
        ln_bf16<<<dim3(512), dim3(256), 0, stream>>>(x, ln2g + i * EE, ln2b + i * EE, xn);
        // FFN1: gelu(xn @ fw1 + fb1) -> ffh (bf16)
        gemm_mfma<EE, 2><<<dim3(32, 32, 1), dim3(256), 0, stream>>>(
            xn, wt + OFF_FW1 + (size_t)i * 131072, fb1 + i * HIDN, ffh,
            nullptr, nullptr, nullptr, nullptr, nullptr, nullptr,
            HIDN, nullptr, nullptr, nullptr);
        // FFN2: x += ffh @ fw2 + fb2
        gemm_mfma<HIDN, 1><<<dim3(32, 16, 1), dim3(256), 0, stream>>>(
            ffh, wt + OFF_FW2 + (size_t)i * 131072, fb2 + i * EE, x,
            nullptr, nullptr, nullptr, nullptr, nullptr, nullptr,
            EE, nullptr, nullptr, nullptr);
    }

    pool_part<<<dim3(16, BB), dim3(256), 0, stream>>>(x, mask, part, pmaskp);
    head_kernel<<<dim3(BB), dim3(256), 0, stream>>>(
        part, pmaskp, hlng, hlnb, hw1, hb1, hw2, hb2, (float*)d_out);

    (void)in_sizes; (void)n_in; (void)out_size; (void)ws_size;
}

// Round 11
// 326.580 us; speedup vs baseline: 1.0698x; 1.0128x over previous
//
#include <hip/hip_runtime.h>
#include <math.h>

// Problem constants (fixed by the reference)
#define BB     2
#define LL     1024
#define CC     4
#define EE     256
#define HH     8
#define DD     32
#define NLAYER 2
#define W1N    257          // WIN+1
#define INPAIR 1028         // C*(WIN+1)
#define KP1    1056         // INPAIR padded to 32
#define HIDN   512
#define NCN    10
#define SCALEF 0.17677669529663687f   // 32^-0.5

typedef short bf16x8 __attribute__((ext_vector_type(8)));
typedef float f32x4  __attribute__((ext_vector_type(4)));
typedef unsigned short u16x4 __attribute__((ext_vector_type(4)));
typedef unsigned short u16x8 __attribute__((ext_vector_type(8)));

__device__ __forceinline__ float gelu_f(float x) {
    return 0.5f * x * (1.0f + erff(x * 0.7071067811865475f));
}
__device__ __forceinline__ unsigned short f2bf(float f) {
    unsigned u = __float_as_uint(f);
    u += 0x7fffu + ((u >> 16) & 1u);      // RNE
    return (unsigned short)(u >> 16);
}
__device__ __forceinline__ float bf2f(unsigned short u) {
    return __uint_as_float((unsigned)u << 16);
}

// ---------------------------------------------------------------------------
// prep_gather: one launch for both weight conversion and the pairwise gather.
// ---------------------------------------------------------------------------
struct PrepDesc {
    const float* src[14];
    int K[14];
    int N[14];
    unsigned long long dst[14];
};

__global__ __launch_bounds__(256) void prep_gather(
    PrepDesc pd, unsigned short* __restrict__ wt,
    const float* __restrict__ xp, unsigned short* __restrict__ flat)
{
    const int bid = blockIdx.x;
    if (bid < 1848) {
        const int mi = bid / 132, k8 = bid - mi * 132;
        const int K = pd.K[mi], N = pd.N[mi];
        const int Kp = (K + 31) & ~31;
        if (k8 * 8 >= Kp) return;
        const float* src = pd.src[mi];
        unsigned short* dst = wt + pd.dst[mi];
        for (int n = threadIdx.x; n < N; n += 256) {
            u16x8 o;
            #pragma unroll
            for (int j = 0; j < 8; ++j) {
                int k = k8 * 8 + j;
                float v = (k < K) ? src[(size_t)k * N + n] : 0.f;
                o[j] = f2bf(v);
            }
            *(u16x8*)(dst + ((size_t)k8 * N + n) * 8) = o;
        }
    } else {
        const int row = bid - 1848;
        const int b = row >> 10, l = row & 1023;
        const float* base = xp + (size_t)b * CC * LL * LL + (size_t)l * LL;
        for (int kp = threadIdx.x; kp < KP1; kp += 256) {
            float v = 0.f;
            if (kp < INPAIR) {
                int c = kp / W1N;
                int w = kp - c * W1N;
                int col = l + w - 128;
                if (col >= 0 && col < LL) v = base[(size_t)c * LL * LL + col];
            }
            flat[(size_t)row * KP1 + kp] = f2bf(v);
        }
    }
}

// ---------------------------------------------------------------------------
// ln_bf16: per-row LayerNorm of fp32 x -> bf16 out. 1 wave per row.
// ---------------------------------------------------------------------------
__global__ __launch_bounds__(256) void ln_bf16(
    const float* __restrict__ x, const float* __restrict__ g,
    const float* __restrict__ bt, unsigned short* __restrict__ out)
{
    const int row = blockIdx.x * 4 + (threadIdx.x >> 6);
    const int lane = threadIdx.x & 63;
    float4 v = *(const float4*)(x + (size_t)row * EE + lane * 4);
    float s = v.x + v.y + v.z + v.w;
    #pragma unroll
    for (int m = 1; m < 64; m <<= 1) s += __shfl_xor(s, m, 64);
    const float mu = s * (1.0f / 256.0f);
    float q2 = 0.f, d;
    d = v.x - mu; q2 += d * d; d = v.y - mu; q2 += d * d;
    d = v.z - mu; q2 += d * d; d = v.w - mu; q2 += d * d;
    #pragma unroll
    for (int m = 1; m < 64; m <<= 1) q2 += __shfl_xor(q2, m, 64);
    const float rstd = rsqrtf(q2 * (1.0f / 256.0f) + 1e-5f);
    float4 gg = *(const float4*)(g + lane * 4);
    float4 bb = *(const float4*)(bt + lane * 4);
    u16x4 o;
    o[0] = f2bf((v.x - mu) * rstd * gg.x + bb.x);
    o[1] = f2bf((v.y - mu) * rstd * gg.y + bb.y);
    o[2] = f2bf((v.z - mu) * rstd * gg.z + bb.z);
    o[3] = f2bf((v.w - mu) * rstd * gg.w + bb.w);
    *(u16x4*)(out + (size_t)row * EE + lane * 4) = o;
}

// ---------------------------------------------------------------------------
// gemm_mfma: out = epi(A_bf16 @ W + bias). No LDS, no barriers. (R5/R8 proven)
// EPI: 0=QKV pack (z: 0=Q A-layout bf16, 1=K swz, 2=V swz)
//      1=residual +=, 2=gelu->bf16, 3=relu->bf16, 4=emb->fp32
// ---------------------------------------------------------------------------
template<int KP, int EPI>
__global__ __launch_bounds__(256) void gemm_mfma(
    const unsigned short* __restrict__ A,
    const unsigned short* wt0, const float* b0, void* o0,
    const unsigned short* wt1, const float* b1, void* o1,
    const unsigned short* wt2, const float* b2, void* o2,
    int N,
    const int* __restrict__ tokens, const float* __restrict__ temb,
    const float* __restrict__ pe)
{
    const int t = threadIdx.x;
    const int w = t >> 6, lane = t & 63;
    const int m0 = blockIdx.x * 64 + w * 16;
    const int n0 = blockIdx.y * 16;
    const unsigned short* WT; const float* bias; void* out;
    if (blockIdx.z == 0)      { WT = wt0; bias = b0; out = o0; }
    else if (blockIdx.z == 1) { WT = wt1; bias = b1; out = o1; }
    else                      { WT = wt2; bias = b2; out = o2; }

    const int q = lane >> 4, li = lane & 15;
    const unsigned short* ap = A + (size_t)(m0 + li) * KP + q * 8;
    const unsigned short* bp = WT + ((size_t)q * N + n0 + li) * 8;
    f32x4 acc = {0.f, 0.f, 0.f, 0.f};
    for (int ks = 0; ks < KP / 32; ++ks) {
        bf16x8 av = *(const bf16x8*)(ap + ks * 32);
        bf16x8 bv = *(const bf16x8*)(bp + (size_t)ks * 32 * N);
        acc = __builtin_amdgcn_mfma_f32_16x16x32_bf16(av, bv, acc, 0, 0, 0);
    }

    const int colg = n0 + li;
    const float bb = bias[colg];
    const int rbase = m0 + q * 4;
    #pragma unroll
    for (int r = 0; r < 4; ++r) {
        const int row = rbase + r;
        float v = acc[r] + bb;
        if constexpr (EPI == 0) {          // QKV -> bf16 attention layouts
            int b = row >> 10, l = row & 1023;
            int h = colg >> 5, d = colg & 31;
            int bh = b * HH + h;
            unsigned short* op = (unsigned short*)out;
            if (blockIdx.z == 0)
                op[((size_t)bh * LL + l) * DD + d] = f2bf(v);
            else if (blockIdx.z == 1)
                op[(size_t)bh * 32768 + (size_t)(d >> 3) * 8192 + (size_t)l * 8 + (d & 7)] = f2bf(v);
            else
                op[(size_t)bh * 32768 + (size_t)(l >> 3) * 256 + (size_t)d * 8 + (l & 7)] = f2bf(v);
        } else if constexpr (EPI == 1) {   // residual accumulate into fp32 out
            float* op = (float*)out;
            op[(size_t)row * N + colg] += v;
        } else if constexpr (EPI == 2) {   // gelu -> bf16
            ((unsigned short*)out)[(size_t)row * N + colg] = f2bf(gelu_f(v));
        } else if constexpr (EPI == 3) {   // relu -> bf16
            ((unsigned short*)out)[(size_t)row * N + colg] = f2bf(fmaxf(v, 0.f));
        } else {                            // emb: + temb[tok] + pe -> fp32
            int tok = tokens[row];
            v += temb[(size_t)tok * EE + colg] + pe[(size_t)(row & 1023) * EE + colg];
            ((float*)out)[(size_t)row * EE + colg] = v;
        }
    }
}

// ---------------------------------------------------------------------------
// attn_part_mfma: flash attention partial, MFMA, zero block barriers.
// Row-per-lane softmax (R10); partial O now stored bf16 (halved traffic).
// Block = 256 thr (4 waves), wave = 16 q-rows. Grid (16 qt | 4 mc, H, B).
// ---------------------------------------------------------------------------
__global__ __launch_bounds__(256, 4) void attn_part_mfma(
    const unsigned short* __restrict__ qb,
    const unsigned short* __restrict__ kswz,
    const unsigned short* __restrict__ vswz,
    const float* __restrict__ bias, const float* __restrict__ mask,
    const float* __restrict__ gate,
    unsigned short* __restrict__ Opart, float* __restrict__ statsM,
    float* __restrict__ statsL)
{
    __shared__ float Sbuf[4][16][68];     // per-wave S tile [q-row][m-col] (+4 pad)
    const int t = threadIdx.x;
    const int wq = t >> 6, lane = t & 63;
    const int li = lane & 15, qd = lane >> 4;
    const int h = blockIdx.y, b = blockIdx.z;
    const int bh = b * HH + h;
    const int qt = blockIdx.x & 15, mc = blockIdx.x >> 4;
    const int q0 = qt * 64 + wq * 16;
    const int mbase = mc * 256;
    const float gh = gate[h];

    const bf16x8 qfrag = *(const bf16x8*)(qb + ((size_t)bh * LL + q0 + li) * DD + qd * 8);
    const unsigned short* kbase = kswz + (size_t)bh * 32768 + (size_t)qd * 8192 + (size_t)li * 8;
    const unsigned short* vbase = vswz + (size_t)bh * 32768 + (size_t)qd * 256 + (size_t)li * 8;
    const float* brow = bias + ((size_t)bh * LL + q0 + li) * LL;
    const float* mrow = mask + (size_t)b * LL;

    float mrun = -3.0e38f, lrun = 0.f;    // for q-row (q0+li), replicated over qd
    f32x4 o0 = {0.f, 0.f, 0.f, 0.f}, o1 = {0.f, 0.f, 0.f, 0.f};

    for (int mtt = 0; mtt < 4; ++mtt) {
        const int m0 = mbase + mtt * 64;
        float4 bv0 = *(const float4*)(brow + m0 + qd * 8);
        float4 bv1 = *(const float4*)(brow + m0 + qd * 8 + 4);
        float4 bv2 = *(const float4*)(brow + m0 + 32 + qd * 8);
        float4 bv3 = *(const float4*)(brow + m0 + 32 + qd * 8 + 4);
        float4 mk0 = *(const float4*)(mrow + m0 + qd * 8);
        float4 mk1 = *(const float4*)(mrow + m0 + qd * 8 + 4);
        float4 mk2 = *(const float4*)(mrow + m0 + 32 + qd * 8);
        float4 mk3 = *(const float4*)(mrow + m0 + 32 + qd * 8 + 4);
        f32x4 S[4];
        #pragma unroll
        for (int ms = 0; ms < 4; ++ms) {
            bf16x8 kf = *(const bf16x8*)(kbase + (size_t)(m0 + ms * 16) * 8);
            f32x4 z = {0.f, 0.f, 0.f, 0.f};
            S[ms] = __builtin_amdgcn_mfma_f32_16x16x32_bf16(qfrag, kf, z, 0, 0, 0);
        }
        #pragma unroll
        for (int ms = 0; ms < 4; ++ms)
            #pragma unroll
            for (int r = 0; r < 4; ++r)
                Sbuf[wq][qd * 4 + r][ms * 16 + li] = S[ms][r];
        float4 s0 = *(const float4*)&Sbuf[wq][li][qd * 8];
        float4 s1 = *(const float4*)&Sbuf[wq][li][qd * 8 + 4];
        float4 s2 = *(const float4*)&Sbuf[wq][li][32 + qd * 8];
        float4 s3 = *(const float4*)&Sbuf[wq][li][32 + qd * 8 + 4];
        float lg[16];
        lg[0]  = fmaf(s0.x, SCALEF, fmaf(gh, bv0.x, (1.0f - mk0.x) * -10000.0f));
        lg[1]  = fmaf(s0.y, SCALEF, fmaf(gh, bv0.y, (1.0f - mk0.y) * -10000.0f));
        lg[2]  = fmaf(s0.z, SCALEF, fmaf(gh, bv0.z, (1.0f - mk0.z) * -10000.0f));
        lg[3]  = fmaf(s0.w, SCALEF, fmaf(gh, bv0.w, (1.0f - mk0.w) * -10000.0f));
        lg[4]  = fmaf(s1.x, SCALEF, fmaf(gh, bv1.x, (1.0f - mk1.x) * -10000.0f));
        lg[5]  = fmaf(s1.y, SCALEF, fmaf(gh, bv1.y, (1.0f - mk1.y) * -10000.0f));
        lg[6]  = fmaf(s1.z, SCALEF, fmaf(gh, bv1.z, (1.0f - mk1.z) * -10000.0f));
        lg[7]  = fmaf(s1.w, SCALEF, fmaf(gh, bv1.w, (1.0f - mk1.w) * -10000.0f));
        lg[8]  = fmaf(s2.x, SCALEF, fmaf(gh, bv2.x, (1.0f - mk2.x) * -10000.0f));
        lg[9]  = fmaf(s2.y, SCALEF, fmaf(gh, bv2.y, (1.0f - mk2.y) * -10000.0f));
        lg[10] = fmaf(s2.z, SCALEF, fmaf(gh, bv2.z, (1.0f - mk2.z) * -10000.0f));
        lg[11] = fmaf(s2.w, SCALEF, fmaf(gh, bv2.w, (1.0f - mk2.w) * -10000.0f));
        lg[12] = fmaf(s3.x, SCALEF, fmaf(gh, bv3.x, (1.0f - mk3.x) * -10000.0f));
        lg[13] = fmaf(s3.y, SCALEF, fmaf(gh, bv3.y, (1.0f - mk3.y) * -10000.0f));
        lg[14] = fmaf(s3.z, SCALEF, fmaf(gh, bv3.z, (1.0f - mk3.z) * -10000.0f));
        lg[15] = fmaf(s3.w, SCALEF, fmaf(gh, bv3.w, (1.0f - mk3.w) * -10000.0f));
        float tm = lg[0];
        #pragma unroll
        for (int j = 1; j < 16; ++j) tm = fmaxf(tm, lg[j]);
        tm = fmaxf(tm, __shfl_xor(tm, 16, 64));
        tm = fmaxf(tm, __shfl_xor(tm, 32, 64));
        const float nm = fmaxf(mrun, tm);
        const float alpha = expf(mrun - nm);
        mrun = nm;
        float p[16];
        float ts = 0.f;
        #pragma unroll
        for (int j = 0; j < 16; ++j) { p[j] = expf(lg[j] - nm); ts += p[j]; }
        ts += __shfl_xor(ts, 16, 64);
        ts += __shfl_xor(ts, 32, 64);
        lrun = lrun * alpha + ts;
        #pragma unroll
        for (int r = 0; r < 4; ++r) {
            const float al = __shfl(alpha, qd * 4 + r, 64);
            o0[r] *= al; o1[r] *= al;
        }
        u16x8 pu0, pu1;
        #pragma unroll
        for (int j = 0; j < 8; ++j) { pu0[j] = f2bf(p[j]); pu1[j] = f2bf(p[8 + j]); }
        const bf16x8 pa0 = *(bf16x8*)&pu0;
        const bf16x8 pa1 = *(bf16x8*)&pu1;
        {
            const unsigned short* v0p = vbase + (size_t)((m0 >> 3) + 0) * 256;
            const unsigned short* v1p = vbase + (size_t)((m0 >> 3) + 4) * 256;
            bf16x8 vf00 = *(const bf16x8*)(v0p);
            bf16x8 vf01 = *(const bf16x8*)(v0p + 16 * 8);
            bf16x8 vf10 = *(const bf16x8*)(v1p);
            bf16x8 vf11 = *(const bf16x8*)(v1p + 16 * 8);
            o0 = __builtin_amdgcn_mfma_f32_16x16x32_bf16(pa0, vf00, o0, 0, 0, 0);
            o1 = __builtin_amdgcn_mfma_f32_16x16x32_bf16(pa0, vf01, o1, 0, 0, 0);
            o0 = __builtin_amdgcn_mfma_f32_16x16x32_bf16(pa1, vf10, o0, 0, 0, 0);
            o1 = __builtin_amdgcn_mfma_f32_16x16x32_bf16(pa1, vf11, o1, 0, 0, 0);
        }
    }
    // ---- write partial O (bf16, unnormalized) + per-row stats ----
    const size_t rowg0 = (size_t)(mc * 2 + b) * LL;
    #pragma unroll
    for (int r = 0; r < 4; ++r) {
        const int row = q0 + qd * 4 + r;
        const size_t rg = rowg0 + row;
        Opart[rg * EE + h * DD + li]      = f2bf(o0[r]);
        Opart[rg * EE + h * DD + 16 + li] = f2bf(o1[r]);
    }
    if (qd == 0) {
        const size_t rg = rowg0 + q0 + li;
        statsM[rg * HH + h] = mrun;
        statsL[rg * HH + h] = lrun;
    }
}

// ---------------------------------------------------------------------------
// attn_merge: combine 4 m-chunk bf16 partials -> aob bf16 [2048][256]
// 512 blocks x 4 rows; u16x4 vector loads.
// ---------------------------------------------------------------------------
__global__ __launch_bounds__(256) void attn_merge(
    const unsigned short* __restrict__ Opart, const float* __restrict__ statsM,
    const float* __restrict__ statsL, const float* __restrict__ mask,
    unsigned short* __restrict__ aob)
{
    const int t = threadIdx.x;
    const int row = blockIdx.x * 4 + (t >> 6);      // global row 0..2047
    const int e4 = (t & 63) * 4;
    const int h = e4 >> 5;
    float m_[4];
    float M = -3.0e38f;
    #pragma unroll
    for (int mc = 0; mc < 4; ++mc) {
        m_[mc] = statsM[((size_t)mc * 2048 + row) * HH + h];
        M = fmaxf(M, m_[mc]);
    }
    float Lsum = 0.f;
    float V[4] = {0.f, 0.f, 0.f, 0.f};
    #pragma unroll
    for (int mc = 0; mc < 4; ++mc) {
        const float sc = expf(m_[mc] - M);
        Lsum = fmaf(statsL[((size_t)mc * 2048 + row) * HH + h], sc, Lsum);
        u16x4 ov = *(const u16x4*)(Opart + ((size_t)mc * 2048 + row) * EE + e4);
        V[0] = fmaf(bf2f(ov[0]), sc, V[0]);
        V[1] = fmaf(bf2f(ov[1]), sc, V[1]);
        V[2] = fmaf(bf2f(ov[2]), sc, V[2]);
        V[3] = fmaf(bf2f(ov[3]), sc, V[3]);
    }
    const float mq = mask[row];
    const float inv = (Lsum > 0.f ? 1.0f / Lsum : 0.f) * mq * mq;
    u16x4 o;
    o[0] = f2bf(V[0] * inv); o[1] = f2bf(V[1] * inv);
    o[2] = f2bf(V[2] * inv); o[3] = f2bf(V[3] * inv);
    *(u16x4*)(aob + (size_t)row * EE + e4) = o;
}

// ---------------------------------------------------------------------------
// pool stage 1: partial sums over 64-row chunks (R5 proven)
// ---------------------------------------------------------------------------
__global__ __launch_bounds__(256) void pool_part(
    const float* __restrict__ x, const float* __restrict__ mask,
    float* __restrict__ part, float* __restrict__ pmask)
{
    const int ch = blockIdx.x, b = blockIdx.y, t = threadIdx.x;
    const int l0 = ch * 64;
    float s = 0.f, ms = 0.f;
    #pragma unroll 4
    for (int i = 0; i < 64; ++i) {
        int l = l0 + i;
        float mm = mask[b * LL + l];
        s = fmaf(x[((size_t)(b * LL + l)) * EE + t], mm, s);
        ms += mm;
    }
    part[(size_t)(b * 16 + ch) * EE + t] = s;
    if (t == 0) pmask[b * 16 + ch] = ms;
}

// ---------------------------------------------------------------------------
// head: pool-reduce + LN + gelu(W1) + W2, one block per batch element (R5)
// ---------------------------------------------------------------------------
__global__ __launch_bounds__(256) void head_kernel(
    const float* __restrict__ part, const float* __restrict__ pmask,
    const float* __restrict__ hg, const float* __restrict__ hb,
    const float* __restrict__ w1, const float* __restrict__ b1,
    const float* __restrict__ w2, const float* __restrict__ b2,
    float* __restrict__ outp)
{
    __shared__ float pn[EE];
    __shared__ float red[4];
    __shared__ float wred[4][NCN];
    const int b = blockIdx.x;
    const int t = threadIdx.x;
    const int wv = t >> 6, lane = t & 63;

    float v = 0.f, msum = 0.f;
    #pragma unroll
    for (int c = 0; c < 16; ++c) {
        v += part[(size_t)(b * 16 + c) * EE + t];
        msum += pmask[b * 16 + c];
    }
    v = v / fmaxf(msum, 1.0f);
    float s = v;
    #pragma unroll
    for (int mm = 1; mm < 64; mm <<= 1) s += __shfl_xor(s, mm, 64);
    if (lane == 0) red[wv] = s;
    __syncthreads();
    const float mu = (red[0] + red[1] + red[2] + red[3]) * (1.0f / 256.0f);
    __syncthreads();
    float d = v - mu;
    float q2 = d * d;
    #pragma unroll
    for (int mm = 1; mm < 64; mm <<= 1) q2 += __shfl_xor(q2, mm, 64);
    if (lane == 0) red[wv] = q2;
    __syncthreads();
    const float var = (red[0] + red[1] + red[2] + red[3]) * (1.0f / 256.0f);
    const float rstd = rsqrtf(var + 1e-5f);
    pn[t] = d * rstd * hg[t] + hb[t];
    __syncthreads();
    float acc = b1[t];
    #pragma unroll 8
    for (int k = 0; k < EE; ++k) acc = fmaf(pn[k], w1[k * EE + t], acc);
    const float g = gelu_f(acc);
    float contrib[NCN];
    #pragma unroll
    for (int c = 0; c < NCN; ++c) contrib[c] = g * w2[(size_t)t * NCN + c];
    #pragma unroll
    for (int mm = 1; mm < 64; mm <<= 1) {
        #pragma unroll
        for (int c = 0; c < NCN; ++c) contrib[c] += __shfl_xor(contrib[c], mm, 64);
    }
    if (lane == 0) {
        #pragma unroll
        for (int c = 0; c < NCN; ++c) wred[wv][c] = contrib[c];
    }
    __syncthreads();
    if (t < NCN)
        outp[b * NCN + t] = b2[t] + wred[0][t] + wred[1][t] + wred[2][t] + wred[3][t];
}

// ---------------------------------------------------------------------------
extern "C" void kernel_launch(void* const* d_in, const int* in_sizes, int n_in,
                              void* d_out, int out_size, void* d_ws, size_t ws_size,
                              hipStream_t stream) {
    const int*   tokens = (const int*)  d_in[0];
    const float* xp     = (const float*)d_in[1];
    const float* bias   = (const float*)d_in[2];
    const float* mask   = (const float*)d_in[3];
    const float* temb   = (const float*)d_in[4];
    const float* pe     = (const float*)d_in[5];
    const float* pw1    = (const float*)d_in[6];
    const float* pb1    = (const float*)d_in[7];
    const float* pw2    = (const float*)d_in[8];
    const float* pb2    = (const float*)d_in[9];
    const float* ln1g   = (const float*)d_in[10];
    const float* ln1b   = (const float*)d_in[11];
    const float* wq     = (const float*)d_in[12];
    const float* wk     = (const float*)d_in[13];
    const float* wv     = (const float*)d_in[14];
    const float* wo     = (const float*)d_in[15];
    const float* bq     = (const float*)d_in[16];
    const float* bk     = (const float*)d_in[17];
    const float* bv     = (const float*)d_in[18];
    const float* bo     = (const float*)d_in[19];
    const float* gate   = (const float*)d_in[20];
    const float* ln2g   = (const float*)d_in[21];
    const float* ln2b   = (const float*)d_in[22];
    const float* fw1    = (const float*)d_in[23];
    const float* fb1    = (const float*)d_in[24];
    const float* fw2    = (const float*)d_in[25];
    const float* fb2    = (const float*)d_in[26];
    const float* hlng   = (const float*)d_in[27];
    const float* hlnb   = (const float*)d_in[28];
    const float* hw1    = (const float*)d_in[29];
    const float* hb1    = (const float*)d_in[30];
    const float* hw2    = (const float*)d_in[31];
    const float* hb2    = (const float*)d_in[32];

    // ------ workspace layout ------
    float* ws = (float*)d_ws;
    const size_t NTOK = (size_t)BB * LL * EE;                 // 524288
    float* x      = ws;                                       // fp32 [2048][256]
    float* statsM = ws + NTOK;                                // [4][2048][8]
    float* statsL = statsM + 65536;
    float* part   = statsL + 65536;                           // [2][16][256]
    float* pmaskp = part + 32 * EE;                           // [32]
    unsigned short* usp = (unsigned short*)(pmaskp + 32);
    usp = (unsigned short*)(((size_t)usp + 15) & ~(size_t)15);
    unsigned short* Opart = usp;                              // bf16 [4][2048][256]
    unsigned short* qb16 = Opart + 4 * NTOK;                  // bf16 [BH][L][32]
    unsigned short* kswz = qb16 + NTOK;                       // bf16 [BH][4][1024][8]
    unsigned short* vswz = kswz + NTOK;                       // bf16 [BH][128][32][8]
    unsigned short* aob  = vswz + NTOK;                       // bf16 [2048][256]
    unsigned short* ffh  = aob + NTOK;                        // bf16 [2048][512]
    unsigned short* ph   = ffh + (size_t)BB * LL * HIDN;      // bf16 [2048][256] (xn alias)
    unsigned short* flat = ph + NTOK;                         // bf16 [2048][1056]
    unsigned short* wt   = flat + (size_t)BB * LL * KP1;      // weight pool

    // weight-pool sub-offsets (ushort units)
    const size_t OFF_PW1 = 0;                         // 1056*256 = 270336
    const size_t OFF_PW2 = 270336;                    // 65536
    const size_t OFF_QKVO = 335872;                   // 8 * 65536
    const size_t OFF_FW1 = 860160;                    // 2 * 131072
    const size_t OFF_FW2 = 1122304;                   // 2 * 131072

    // ------ prep descriptors ------
    PrepDesc pd;
    pd.src[0] = pw1;  pd.K[0] = INPAIR; pd.N[0] = EE;  pd.dst[0] = OFF_PW1;
    pd.src[1] = pw2;  pd.K[1] = EE;     pd.N[1] = EE;  pd.dst[1] = OFF_PW2;
    for (int l = 0; l < 2; ++l) {
        const float* srcs[4] = {wq + l * EE * EE, wk + l * EE * EE,
                                wv + l * EE * EE, wo + l * EE * EE};
        for (int wch = 0; wch < 4; ++wch) {
            int mi = 2 + l * 4 + wch;
            pd.src[mi] = srcs[wch]; pd.K[mi] = EE; pd.N[mi] = EE;
            pd.dst[mi] = OFF_QKVO + (size_t)(l * 4 + wch) * 65536;
        }
    }
    for (int l = 0; l < 2; ++l) {
        pd.src[10 + l] = fw1 + (size_t)l * EE * HIDN;
        pd.K[10 + l] = EE;  pd.N[10 + l] = HIDN;
        pd.dst[10 + l] = OFF_FW1 + (size_t)l * 131072;
        pd.src[12 + l] = fw2 + (size_t)l * HIDN * EE;
        pd.K[12 + l] = HIDN; pd.N[12 + l] = EE;
        pd.dst[12 + l] = OFF_FW2 + (size_t)l * 131072;
    }

    // ------ weight prep + pairwise gather (one launch) ------
    prep_gather<<<dim3(1848 + 2048), dim3(256), 0, stream>>>(pd, wt, xp, flat);

    // MLP1: relu(flat @ w1 + b1) -> ph (bf16)
    gemm_mfma<KP1, 3><<<dim3(32, 16, 1), dim3(256), 0, stream>>>(
        flat, wt + OFF_PW1, pb1, ph, nullptr, nullptr, nullptr,
        nullptr, nullptr, nullptr, EE, nullptr, nullptr, nullptr);
    // MLP2: ph @ w2 + b2 + temb + pe -> x (fp32)
    gemm_mfma<EE, 4><<<dim3(32, 16, 1), dim3(256), 0, stream>>>(
        ph, wt + OFF_PW2, pb2, x, nullptr, nullptr, nullptr,
        nullptr, nullptr, nullptr, EE, tokens, temb, pe);

    for (int i = 0; i < NLAYER; ++i) {
        unsigned short* xn = ph;   // ph dead after MLP2; reused as LN output
        // LN1 -> xn (bf16)
        ln_bf16<<<dim3(512), dim3(256), 0, stream>>>(x, ln1g + i * EE, ln1b + i * EE, xn);
        // QKV (one launch, z = 3) -> bf16 attention layouts
        gemm_mfma<EE, 0><<<dim3(32, 16, 3), dim3(256), 0, stream>>>(
            xn,
            wt + OFF_QKVO + (size_t)(i * 4 + 0) * 65536, bq + i * EE, qb16,
            wt + OFF_QKVO + (size_t)(i * 4 + 1) * 65536, bk + i * EE, kswz,
            wt + OFF_QKVO + (size_t)(i * 4 + 2) * 65536, bv + i * EE, vswz,
            EE, nullptr, nullptr, nullptr);
        // flash attention partials (m-split x4, bf16 partials) + merge
        attn_part_mfma<<<dim3(64, HH, BB), dim3(256), 0, stream>>>(
            qb16, kswz, vswz, bias, mask, gate + i * HH, Opart, statsM, statsL);
        attn_merge<<<dim3(512), dim3(256), 0, stream>>>(Opart, statsM, statsL, mask, aob);
        // O-proj + residual: x += aob @ wo + bo
        gemm_mfma<EE, 1><<<dim3(32, 16, 1), dim3(256), 0, stream>>>(
            aob, wt + OFF_QKVO + (size_t)(i * 4 + 3) * 65536, bo + i * EE, x,
            nullptr, nullptr, nullptr, nullptr, nullptr, nullptr,
            EE, nullptr, nullptr, nullptr);
        // LN2 -> xn
        ln_bf16<<<dim3(512), dim3(256), 0, stream>>>(x, ln2g + i * EE, ln2b + i * EE, xn);
        // FFN1: gelu(xn @ fw1 + fb1) -> ffh (bf16)
        gemm_mfma<EE, 2><<<dim3(32, 32, 1), dim3(256), 0, stream>>>(
            xn, wt + OFF_FW1 + (size_t)i * 131072, fb1 + i * HIDN, ffh,
            nullptr, nullptr, nullptr, nullptr, nullptr, nullptr,
            HIDN, nullptr, nullptr, nullptr);
        // FFN2: x += ffh @ fw2 + fb2
        gemm_mfma<HIDN, 1><<<dim3(32, 16, 1), dim3(256), 0, stream>>>(
            ffh, wt + OFF_FW2 + (size_t)i * 131072, fb2 + i * EE, x,
            nullptr, nullptr, nullptr, nullptr, nullptr, nullptr,
            EE, nullptr, nullptr, nullptr);
    }

    pool_part<<<dim3(16, BB), dim3(256), 0, stream>>>(x, mask, part, pmaskp);
    head_kernel<<<dim3(BB), dim3(256), 0, stream>>>(
        part, pmaskp, hlng, hlnb, hw1, hb1, hw2, hb2, (float*)d_out);

    (void)in_sizes; (void)n_in; (void)out_size; (void)ws_size;
}